// Round 11
// baseline (403.468 us; speedup 1.0000x reference)
//
#include <hip/hip_runtime.h>

// Correlation cost volume: B=4, C=256, H=W=192, MAX_DISP=4 -> 81 displacements.
// out[b, dy*9+dx, y, x] = (1/C) * sum_c F[b,c,y,x] * Spad[b,c,y+dy-4,x+dx-4]
//
// R11 = R10 MFMA Gram-band (verified: fragment layout, epilogue scatter,
//      numerics) with the staging feed rebuilt:
//      (1) octet tasks: (row, k-octet, u) -> 8 coalesced channel-dword loads
//          + ONE contiguous ds_write_b128 in fragment order (was 48 dwords +
//          scattered packing per thread per step; now 37 + 4.6 b128 writes).
//      (2) cross-step register prefetch of the S gather (T14 issue-early/
//          write-late): latency hides behind barrier+MFMA+next write phase.
//      (3) lgk-only barriers (R9-verified) keep prefetch loads in flight;
//          OOB zero-fill hoisted out of the loop (single buffer, step-
//          invariant slots).

#define MAXD 4
#define WINW 9
#define NDISP 81

constexpr int B_ = 4, C_ = 256, H_ = 192, W_ = 192;
constexpr int PHW = H_ * W_;             // 36864
constexpr int YS = 3;                    // y rows per block
constexpr int DS = 3;                    // dy values per block
constexpr int XS = 64;                   // x cols per block
constexpr int VR = YS + DS - 1;          // 5 staged S rows
constexpr int NUT = 5;                   // u-tiles of 16
constexpr int KB = 32;                   // channels per K-step
constexpr int NK = C_ / KB;              // 8
constexpr int NTHREADS = 512;            // 8 waves

constexpr int S_USHORT = VR * NUT * 512; // 12800 bf16
constexpr int F_USHORT = YS * 4 * 512;   // 6144 bf16
constexpr int LDS_USHORT = S_USHORT + F_USHORT;  // 37,888 B

constexpr int S_TASKS = VR * 4 * 80;     // 1600: (vr, kh, u)
constexpr int F_TASKS = YS * 4 * 64;     // 768:  (yy, kh, x)

constexpr int NYS = H_ / YS;             // 64
constexpr int NDS = WINW / DS;           // 3
constexpr int NXS = W_ / XS;             // 3
constexpr int NBLK = B_ * NYS * NDS * NXS;  // 2304
constexpr int PER_XCD = NBLK / 8;        // 288 (exact)

typedef __attribute__((ext_vector_type(8))) short bf16x8;
typedef __attribute__((ext_vector_type(4))) float f32x4;

// float -> bf16 (round-to-nearest-even) — R10-verified numerics
__device__ __forceinline__ unsigned f2bf(float f) {
    unsigned u = __float_as_uint(f);
    return (u + 0x7FFFu + ((u >> 16) & 1u)) >> 16;
}

// LDS-only barrier (R9-verified): global loads stay in flight across it.
__device__ __forceinline__ void wg_barrier_lds() {
    asm volatile("s_waitcnt lgkmcnt(0)" ::: "memory");
    __builtin_amdgcn_s_barrier();
    asm volatile("" ::: "memory");
}

__global__ __launch_bounds__(NTHREADS, 4)
void corr_kernel(const float* __restrict__ F, const float* __restrict__ S,
                 float* __restrict__ O) {
    __shared__ __align__(16) unsigned short lds[LDS_USHORT];

    const int tid  = threadIdx.x;
    const int lane = tid & 63;
    const int wid  = tid >> 6;           // wave 0..7
    const int xt   = wid & 3;            // wave's x-tile (16 cols)
    const int uh   = wid >> 2;           // wave's u-half (0/1)
    const int utw  = xt + uh;            // wave's u-tile index 0..4

    // ---- XCD-bijective swizzle (R10): 2304 = 8 x 288, xs fastest ----
    const int id = blockIdx.x;
    const int lg = (id & 7) * PER_XCD + (id >> 3);
    const int xs     = lg % NXS;
    const int t1     = lg / NXS;
    const int dstrip = t1 % NDS;
    const int t2     = t1 / NDS;
    const int ystrip = t2 % NYS;
    const int b      = t2 / NYS;
    const int Y0 = ystrip * YS, D0 = dstrip * DS, x0 = xs * XS;
    const int vbase = Y0 + D0 - MAXD;
    const int ubase = x0 - 8;

    const float* Fb = F + (long)b * C_ * PHW;
    const float* Sb = S + (long)b * C_ * PHW;

    // ---- S octet tasks: t -> (vr, kh, u). 8 channel dwords, 1 b128 write.
    unsigned sOff[4]; int sIdx[4]; bool sOk[4], sAct[4];
    #pragma unroll
    for (int q = 0; q < 4; ++q) {
        const int t   = tid + q * NTHREADS;
        const bool a  = (t < S_TASKS);
        const int tt  = a ? t : 0;
        const int u   = tt % 80;
        const int rest = tt / 80;        // < 20
        const int kh  = rest & 3;
        const int vr  = rest >> 2;       // < 5
        const int v   = vbase + vr;
        const int ua  = ubase + u;
        const bool ok = a && ((unsigned)v < (unsigned)H_) &&
                             ((unsigned)ua < (unsigned)W_);
        sAct[q] = a; sOk[q] = ok;
        sIdx[q] = (vr * 5 + (u >> 4)) * 512 + kh * 128 + (u & 15) * 8;
        sOff[q] = (unsigned)(kh * 8 * PHW + (ok ? v : 0) * W_ + (ok ? ua : 0));
    }
    // ---- F octet tasks: t -> (yy, kh, x); always in-bounds.
    unsigned fOff[2]; int fIdx[2]; bool fAct[2];
    #pragma unroll
    for (int q = 0; q < 2; ++q) {
        const int t   = tid + q * NTHREADS;
        const bool a  = (t < F_TASKS);
        const int tt  = a ? t : 0;
        const int x   = tt & 63;
        const int kh  = (tt >> 6) & 3;
        const int yy  = tt >> 8;         // < 3
        fAct[q] = a;
        fIdx[q] = S_USHORT + (yy * 4 + (x >> 4)) * 512 + kh * 128 + (x & 15) * 8;
        fOff[q] = (unsigned)(kh * 8 * PHW + (Y0 + yy) * W_ + x0 + x);
    }

    // ---- zero OOB S slots ONCE (step-invariant, never rewritten) ----
    {
        uint4 z; z.x = z.y = z.z = z.w = 0u;
        #pragma unroll
        for (int q = 0; q < 4; ++q)
            if (sAct[q] && !sOk[q]) *(uint4*)(&lds[sIdx[q]]) = z;
    }

    // ---- accumulators: 9 Gram tiles per wave ----
    f32x4 acc[3][3];
    #pragma unroll
    for (int yy = 0; yy < 3; ++yy)
        #pragma unroll
        for (int dd = 0; dd < 3; ++dd)
            acc[yy][dd] = (f32x4){0.f, 0.f, 0.f, 0.f};

    // ---- prologue: prefetch step 0's S gather into registers ----
    float sv[4][8];
    #pragma unroll
    for (int q = 0; q < 4; ++q) {
        if (sOk[q]) {
            const float* p = Sb + sOff[q];
            #pragma unroll
            for (int j = 0; j < 8; ++j) sv[q][j] = p[(long)j * PHW];
        }
        sOff[q] += KB * PHW;
    }

    for (int step = 0; step < NK; ++step) {
        // (1) F: load in-phase (L2-hot, shared across dstrips) ---------------
        float fv[2][8];
        #pragma unroll
        for (int q = 0; q < 2; ++q) {
            if (fAct[q]) {
                const float* p = Fb + fOff[q];
                #pragma unroll
                for (int j = 0; j < 8; ++j) fv[q][j] = p[(long)j * PHW];
            }
            fOff[q] += KB * PHW;
        }
        // (2) write staged S regs -> LDS (1 contiguous b128 per task) --------
        #pragma unroll
        for (int q = 0; q < 4; ++q) {
            if (sOk[q]) {
                uint4 v;
                v.x = f2bf(sv[q][0]) | (f2bf(sv[q][1]) << 16);
                v.y = f2bf(sv[q][2]) | (f2bf(sv[q][3]) << 16);
                v.z = f2bf(sv[q][4]) | (f2bf(sv[q][5]) << 16);
                v.w = f2bf(sv[q][6]) | (f2bf(sv[q][7]) << 16);
                *(uint4*)(&lds[sIdx[q]]) = v;
            }
        }
        // (3) issue step k+1's S gather (stays in flight across barriers) ----
        if (step + 1 < NK) {
            #pragma unroll
            for (int q = 0; q < 4; ++q) {
                if (sOk[q]) {
                    const float* p = Sb + sOff[q];
                    #pragma unroll
                    for (int j = 0; j < 8; ++j) sv[q][j] = p[(long)j * PHW];
                }
                sOff[q] += KB * PHW;
            }
        }
        // (4) write F ---------------------------------------------------------
        #pragma unroll
        for (int q = 0; q < 2; ++q) {
            if (fAct[q]) {
                uint4 v;
                v.x = f2bf(fv[q][0]) | (f2bf(fv[q][1]) << 16);
                v.y = f2bf(fv[q][2]) | (f2bf(fv[q][3]) << 16);
                v.z = f2bf(fv[q][4]) | (f2bf(fv[q][5]) << 16);
                v.w = f2bf(fv[q][6]) | (f2bf(fv[q][7]) << 16);
                *(uint4*)(&lds[fIdx[q]]) = v;
            }
        }
        wg_barrier_lds();

        // (5) fragment reads: linear, conflict-free (R10-verified) -----------
        bf16x8 A[5], Bf[3];
        #pragma unroll
        for (int vr = 0; vr < 5; ++vr)
            A[vr] = *(const bf16x8*)(&lds[(vr * 5 + utw) * 512 + lane * 8]);
        #pragma unroll
        for (int yy = 0; yy < 3; ++yy)
            Bf[yy] = *(const bf16x8*)(&lds[S_USHORT + (yy * 4 + xt) * 512
                                           + lane * 8]);
        #pragma unroll
        for (int yy = 0; yy < 3; ++yy)
            #pragma unroll
            for (int dd = 0; dd < 3; ++dd)
                acc[yy][dd] = __builtin_amdgcn_mfma_f32_16x16x32_bf16(
                    A[yy + dd], Bf[yy], acc[yy][dd], 0, 0, 0);

        wg_barrier_lds();   // all reads done before next step's writes
    }

    // ---- epilogue (R10-verified): scatter the valid diagonals ----
    const float scale = 1.0f / (float)C_;
    const int col   = lane & 15;
    const int rowb  = (lane >> 4) * 4;
    const int x_abs = x0 + xt * 16 + col;
    #pragma unroll
    for (int r = 0; r < 4; ++r) {
        const int dx = uh * 16 + rowb + r - col - 4;
        if (0 <= dx && dx < WINW) {
            #pragma unroll
            for (int yy = 0; yy < 3; ++yy)
                #pragma unroll
                for (int dd = 0; dd < 3; ++dd) {
                    const int d = (D0 + dd) * WINW + dx;
                    O[((long)(b * NDISP + d) * H_ + (Y0 + yy)) * W_ + x_abs]
                        = acc[yy][dd][r] * scale;
                }
        }
    }
}

extern "C" void kernel_launch(void* const* d_in, const int* in_sizes, int n_in,
                              void* d_out, int out_size, void* d_ws, size_t ws_size,
                              hipStream_t stream) {
    const float* F = (const float*)d_in[0];
    const float* S = (const float*)d_in[1];
    float* O = (float*)d_out;
    dim3 grid(NBLK, 1, 1);   // 2304 eight-wave blocks
    dim3 block(NTHREADS);
    corr_kernel<<<grid, block, 0, stream>>>(F, S, O);
}